// Round 13
// baseline (459.596 us; speedup 1.0000x reference)
//
#include <hip/hip_runtime.h>

#define KN 100000
#define KEG 600000
#define KE 600000
#define NB 98  // ceil(KN/1024) scan blocks
#define LOG2E 1.4426950408889634f
#define LN2 0.6931471805599453f

// k_front block ranges
#define FB_PREP 391
#define FB_CVEC 33
#define FB_HIST 2344
#define FB_T0 6250  // 16 nodes/block (4 per wave)

using u16 = unsigned short;
typedef __bf16 bf16x8 __attribute__((ext_vector_type(8)));
typedef float f32x4 __attribute__((ext_vector_type(4)));
typedef float f32x2 __attribute__((ext_vector_type(2)));

__device__ __forceinline__ float b2f(u16 u) { return __uint_as_float(((unsigned)u) << 16); }
__device__ __forceinline__ u16 f2b(float f) {
  unsigned u = __float_as_uint(f);
  u += 0x7FFF + ((u >> 16) & 1);  // round-to-nearest-even
  return (u16)(u >> 16);
}
__device__ __forceinline__ int imin(int a, int b) { return a < b ? a : b; }
__device__ __forceinline__ float fexp2(float x) {
#if __has_builtin(__builtin_amdgcn_exp2f)
  return __builtin_amdgcn_exp2f(x);
#else
  return __expf(x * LN2);
#endif
}

// async global->LDS 16B copy (no VGPR round-trip). LDS dest is wave-uniform
// base + lane*16; callers pass per-lane pointers laid out exactly that way.
__device__ __forceinline__ void gload_lds16(const void* g, void* l) {
  __builtin_amdgcn_global_load_lds(
      (const __attribute__((address_space(1))) unsigned int*)g,
      (__attribute__((address_space(3))) unsigned int*)l,
      16, 0, 0);
}

// ---------------- fused front: prep + cvec + hist + transform0 ----------------
// wm1t: 36 tiles x 5 frags x 512 (tiles 34..35 = staging pad, never computed).
// Tiles 0..32: Wm1 rows 0..127 (frags 0..3) and K-ext rows [w128,w129,bm1]
// (frag 4), ALL x LOG2E. Tile 33 (owned by cvec range): linear composite
// c=B160@wm2 natural units, c_hi col0 / c_lo col1.
// R21: hist captures the atomicAdd return (slot within dst row) -> tmp_pos[e],
// making k_fill atomic-free. R24: transform0 = 6250 blocks x 16 nodes.
__global__ __launch_bounds__(256) void k_front(
    const float* __restrict__ pos, const float* __restrict__ W0,
    const float* __restrict__ att_s, const float* __restrict__ att_d,
    const float* __restrict__ wm1, const float* __restrict__ bm1,
    const float* __restrict__ wm2, const float* __restrict__ w1,
    const int* __restrict__ gdst,
    u16* __restrict__ wm1t, u16* __restrict__ w1t, float2* __restrict__ wsc2,
    float* __restrict__ w2sum, int* __restrict__ counts, int* __restrict__ tmp_pos,
    u16* __restrict__ h, float* __restrict__ a_s, float* __restrict__ a_d) {
  int bid = blockIdx.x;
  if (bid < FB_PREP) {
    int idx = bid * 256 + threadIdx.x;
    if (idx < 33 * 5 * 512) {  // tiles 0..32 only
      int j = idx & 7;
      int lane = (idx >> 3) & 63;
      int f = (idx >> 9) % 5;
      int nt = idx / (512 * 5);
      int n = nt * 16 + (lane & 15);
      float v = 0.f;
      if (n < 520) {
        if (f < 4) {
          int k = f * 32 + (lane >> 4) * 8 + j;
          v = wm1[k * 520 + n] * LOG2E;
        } else {
          int kk = (lane >> 4) * 8 + j;
          if (kk == 0) v = wm1[128 * 520 + n] * LOG2E;
          else if (kk == 1) v = wm1[129 * 520 + n] * LOG2E;
          else if (kk == 2) v = bm1[n] * LOG2E;
        }
      }
      wm1t[idx] = f2b(v);
    }
    if (idx < 33 * 64) {
      int lane = idx & 63, nt = idx >> 6;
      int col = nt * 16 + (lane & 15);
      float w2 = (col < 520) ? wm2[col] : 0.f;
      float2 p; p.x = w2; p.y = -LN2 * w2;
      wsc2[idx] = p;
    }
    if (idx < 4 * 2 * 64 * 8) {  // W1 -> MFMA B frags
      int j = idx & 7;
      int lane = (idx >> 3) & 63;
      int kt = (idx >> 9) & 1;
      int nt = idx >> 10;
      int n = nt * 16 + (lane & 15);
      int k = kt * 32 + (lane >> 4) * 8 + j;
      w1t[idx] = f2b(w1[k * 64 + n]);
    }
  } else if (bid < FB_PREP + FB_CVEC) {
    // cvec: c_k = sum_h B160[k][h]*wm2[h]; w = row index 0..130; w==131 -> w2sum
    int lane = threadIdx.x & 63;
    int w = (bid - FB_PREP) * 4 + (threadIdx.x >> 6);
    float x = 0.f;
    if (w <= 129) {
      const float* row = wm1 + (size_t)w * 520;
#pragma unroll
      for (int j = 0; j < 8; ++j) x += row[j * 64 + lane] * wm2[j * 64 + lane];
      if (lane < 8) x += row[512 + lane] * wm2[512 + lane];
    } else if (w == 130) {
#pragma unroll
      for (int j = 0; j < 8; ++j) x += bm1[j * 64 + lane] * wm2[j * 64 + lane];
      if (lane < 8) x += bm1[512 + lane] * wm2[512 + lane];
    } else if (w == 131) {
#pragma unroll
      for (int j = 0; j < 8; ++j) x += wm2[j * 64 + lane];
      if (lane < 8) x += wm2[512 + lane];
    }
    for (int off = 1; off < 64; off <<= 1) x += __shfl_xor(x, off);
    if (w <= 130 && lane < 16) {
      int f = w >> 5, kk = w & 31;
      int qq = kk >> 3, jj = kk & 7;
      u16 chi = f2b(x);
      float v = (lane == 0) ? x : (lane == 1 ? (x - b2f(chi)) : 0.f);
      wm1t[(33 * 5 + f) * 512 + (qq * 16 + lane) * 8 + jj] = f2b(v);
    } else if (w == 131 && lane == 0) {
      w2sum[0] = x;
    }
  } else if (bid < FB_PREP + FB_CVEC + FB_HIST) {
    int e = (bid - (FB_PREP + FB_CVEC)) * 256 + threadIdx.x;
    if (e < KEG) tmp_pos[e] = atomicAdd(counts + gdst[e], 1);
  } else {
    // transform0: h = pos @ W0, a_s/a_d reductions. 6250 blocks x 16 nodes
    // (4 per wave, per-node math identical to the 1-node/wave version).
    int lane = threadIdx.x & 63;
    int wave = threadIdx.x >> 6;
    int nb = (bid - (FB_PREP + FB_CVEC + FB_HIST)) * 16 + wave * 4;
#pragma unroll
    for (int i = 0; i < 4; ++i) {
      int n = nb + i;
      float p0 = pos[n * 3 + 0], p1 = pos[n * 3 + 1], p2 = pos[n * 3 + 2];
      float hv = p0 * W0[lane] + p1 * W0[64 + lane] + p2 * W0[128 + lane];
      h[n * 64 + lane] = f2b(hv);
      float s = hv * att_s[lane];
      float d = hv * att_d[lane];
      for (int off = 1; off < 64; off <<= 1) { s += __shfl_xor(s, off); d += __shfl_xor(d, off); }
      if (lane == 0) { a_s[n] = s; a_d[n] = d; }
    }
  }
}

// ---------------- CSR build (R24: rows padded to 4 -> int4 group loads) ----
// Scan runs over cp = (count+3)&~3 so every row_start is 4-aligned; deg stays
// exact (counts); pad slots are never read (walks bounded by deg).

__global__ __launch_bounds__(1024) void k_scan_block(
    const int* __restrict__ counts, int* __restrict__ incl, int* __restrict__ bsum) {
  int gid = blockIdx.x * 1024 + threadIdx.x;
  int lane = threadIdx.x & 63, w = threadIdx.x >> 6;
  int x = (gid < KN) ? ((counts[gid] + 3) & ~3) : 0;
  for (int off = 1; off < 64; off <<= 1) {
    int y = __shfl_up(x, off);
    if (lane >= off) x += y;
  }
  __shared__ int wtot[16];
  if (lane == 63) wtot[w] = x;
  __syncthreads();
  if (w == 0 && lane < 16) {
    int t = wtot[lane];
    for (int off = 1; off < 16; off <<= 1) {
      int y = __shfl_up(t, off);
      if (lane >= off) t += y;
    }
    wtot[lane] = t;
  }
  __syncthreads();
  if (w > 0) x += wtot[w - 1];
  if (gid < KN) incl[gid] = x;
  if (threadIdx.x == 1023) bsum[blockIdx.x] = x;
}

__global__ __launch_bounds__(64) void k_scan_bsum(const int* __restrict__ bsum, int* __restrict__ boff) {
  int lane = threadIdx.x;
  int x0 = (lane < NB) ? bsum[lane] : 0;
  int x1 = (64 + lane < NB) ? bsum[64 + lane] : 0;
  int i0 = x0, i1 = x1;
  for (int off = 1; off < 64; off <<= 1) {
    int y0 = __shfl_up(i0, off), y1 = __shfl_up(i1, off);
    if (lane >= off) { i0 += y0; i1 += y1; }
  }
  int tot0 = __shfl(i0, 63);
  if (lane < NB) boff[lane] = i0 - x0;
  if (64 + lane < NB) boff[64 + lane] = i1 - x1 + tot0;
}

__global__ __launch_bounds__(1024) void k_scan_final(
    const int* __restrict__ incl, const int* __restrict__ counts,
    const int* __restrict__ boff, int* __restrict__ row_start) {
  int gid = blockIdx.x * 1024 + threadIdx.x;
  if (gid < KN) {
    int cp = (counts[gid] + 3) & ~3;
    row_start[gid] = incl[gid] - cp + boff[blockIdx.x];
  }
}

// fill CSR (R21): ATOMIC-FREE — slot was captured during the hist pass.
__global__ __launch_bounds__(256) void k_fill(
    const int* __restrict__ gsrc, const int* __restrict__ gdst,
    const int* __restrict__ row_start, const int* __restrict__ tmp_pos,
    int* __restrict__ csr_src) {
  int e = blockIdx.x * 256 + threadIdx.x;
  if (e >= KEG) return;
  int d = gdst[e];
  csr_src[row_start[d] + tmp_pos[e]] = gsrc[e];
}

// ---------------- GAT layers ----------------

// FUSED agg(L0) + transform1. Block = 16 nodes, grid 6250; each wave
// aggregates 4 nodes (phase A), then computes one column tile (phase B).
// 4-aligned rows -> int4 group index loads.
__global__ __launch_bounds__(256) void k_aggt1(
    const int* __restrict__ row_start, const int* __restrict__ counts,
    const int* __restrict__ csr_src, const float* __restrict__ a_s0,
    const float* __restrict__ a_d0, const u16* __restrict__ h0,
    const float* __restrict__ b0, const u16* __restrict__ w1t,
    const float* __restrict__ as1, const float* __restrict__ ad1,
    u16* __restrict__ h1, float* __restrict__ a_s1, float* __restrict__ a_d1) {
  __shared__ u16 xb[16][72];        // 16 rows x (64 + 8 pad) bf16 = 2304 B
  __shared__ float psum[2][4][16];  // [s/d][wave][node] partials, 512 B
  int lane = threadIdx.x & 63;
  int wave = threadIdx.x >> 6;
  int nodebase = blockIdx.x * 16;   // grid 6250 -> 16*6250 = 100000 exactly

  // ---- phase A: each wave aggregates 4 nodes (lane = channel) ----
  int st0 = row_start[nodebase + wave * 4 + 0];
  int st1 = row_start[nodebase + wave * 4 + 1];
  int st2 = row_start[nodebase + wave * 4 + 2];
  int st3 = row_start[nodebase + wave * 4 + 3];
  int dg0 = counts[nodebase + wave * 4 + 0];
  int dg1 = counts[nodebase + wave * 4 + 1];
  int dg2 = counts[nodebase + wave * 4 + 2];
  int dg3 = counts[nodebase + wave * 4 + 3];
  float adn0 = a_d0[nodebase + wave * 4 + 0];
  float adn1 = a_d0[nodebase + wave * 4 + 1];
  float adn2 = a_d0[nodebase + wave * 4 + 2];
  float adn3 = a_d0[nodebase + wave * 4 + 3];
#pragma unroll
  for (int i = 0; i < 4; ++i) {
    int start = i == 0 ? st0 : (i == 1 ? st1 : (i == 2 ? st2 : st3));
    int deg   = i == 0 ? dg0 : (i == 1 ? dg1 : (i == 2 ? dg2 : dg3));
    float adn = i == 0 ? adn0 : (i == 1 ? adn1 : (i == 2 ? adn2 : adn3));
    float acc = 0.f, den = 0.f;
    int j = 0;
    for (; j + 4 <= deg; j += 4) {
      int4 sv = *(const int4*)(csr_src + start + j);  // 4-aligned row
      int s0 = sv.x, s1 = sv.y, s2 = sv.z, s3 = sv.w;
      float al0 = a_s0[s0] + adn; al0 = al0 > 0.f ? al0 : 0.2f * al0;
      float al1 = a_s0[s1] + adn; al1 = al1 > 0.f ? al1 : 0.2f * al1;
      float al2 = a_s0[s2] + adn; al2 = al2 > 0.f ? al2 : 0.2f * al2;
      float al3 = a_s0[s3] + adn; al3 = al3 > 0.f ? al3 : 0.2f * al3;
      float w0 = __expf(al0), w1 = __expf(al1);
      float w2 = __expf(al2), w3 = __expf(al3);
      float h0v = b2f(h0[s0 * 64 + lane]);
      float h1v = b2f(h0[s1 * 64 + lane]);
      float h2v = b2f(h0[s2 * 64 + lane]);
      float h3v = b2f(h0[s3 * 64 + lane]);
      den += (w0 + w1) + (w2 + w3);
      acc += w0 * h0v + w1 * h1v + w2 * h2v + w3 * h3v;
    }
    for (; j < deg; ++j) {
      int s0 = csr_src[start + j];
      float al = a_s0[s0] + adn; al = al > 0.f ? al : 0.2f * al;
      float w0 = __expf(al);
      den += w0;
      acc += w0 * b2f(h0[s0 * 64 + lane]);
    }
    float v = acc / (den + 1e-16f) + b0[lane];
    v = v > 0.f ? v : expm1f(v);
    xb[wave * 4 + i][lane] = f2b(v);
  }
  __syncthreads();  // all 16 rows visible to all waves

  // ---- phase B: wave w computes column tile nt=w for all 16 nodes ----
  int m = lane & 15, q = lane >> 4;
  const u16* row = xb[m];
  bf16x8 A0 = *(const bf16x8*)(row + q * 8);       // k 0..31
  bf16x8 A1 = *(const bf16x8*)(row + 32 + q * 8);  // k 32..63

  const bf16x8* bt = (const bf16x8*)w1t;
  int nt = wave;
  int col = nt * 16 + m;
  float asv = as1[col], adv = ad1[col];
  f32x4 acc = {0.f, 0.f, 0.f, 0.f};
  acc = __builtin_amdgcn_mfma_f32_16x16x32_bf16(A0, bt[(nt * 2 + 0) * 64 + lane], acc, 0, 0, 0);
  acc = __builtin_amdgcn_mfma_f32_16x16x32_bf16(A1, bt[(nt * 2 + 1) * 64 + lane], acc, 0, 0, 0);
#pragma unroll
  for (int r = 0; r < 4; ++r) {  // C/D: col=lane&15, row(node)=q*4+r
    int rown = nodebase + q * 4 + r;
    h1[rown * 64 + col] = f2b(acc[r]);
    float s = acc[r] * asv, d = acc[r] * adv;
    s += __shfl_xor(s, 1); d += __shfl_xor(d, 1);
    s += __shfl_xor(s, 2); d += __shfl_xor(d, 2);
    s += __shfl_xor(s, 4); d += __shfl_xor(d, 4);
    s += __shfl_xor(s, 8); d += __shfl_xor(d, 8);
    if (m == 0) { psum[0][wave][q * 4 + r] = s; psum[1][wave][q * 4 + r] = d; }
  }
  __syncthreads();

  // ---- cross-wave reduction of a_s1/a_d1 partials ----
  if (threadIdx.x < 16) {
    int i = threadIdx.x;
    a_s1[nodebase + i] = psum[0][0][i] + psum[0][1][i] + psum[0][2][i] + psum[0][3][i];
    a_d1[nodebase + i] = psum[1][0][i] + psum[1][1][i] + psum[1][2][i] + psum[1][3][i];
  }
}

// aggregate layer 1 (weights inline, 4-way ILP, int4 idx loads) -> x12 bf16.
__global__ __launch_bounds__(256) void k_gat_agg(
    const int* __restrict__ row_start, const int* __restrict__ counts,
    const int* __restrict__ csr_src, const float* __restrict__ a_s,
    const float* __restrict__ a_d, const u16* __restrict__ h,
    const float* __restrict__ bias, u16* __restrict__ xout) {
  int lane = threadIdx.x & 63;
  int n = blockIdx.x * 4 + (threadIdx.x >> 6);  // grid covers KN exactly
  int start = row_start[n], deg = counts[n];
  float adn = a_d[n];
  float acc = 0.f, den = 0.f;
  int j = 0;
  for (; j + 4 <= deg; j += 4) {
    int4 sv = *(const int4*)(csr_src + start + j);  // 4-aligned row
    int s0 = sv.x, s1 = sv.y, s2 = sv.z, s3 = sv.w;
    float al0 = a_s[s0] + adn; al0 = al0 > 0.f ? al0 : 0.2f * al0;
    float al1 = a_s[s1] + adn; al1 = al1 > 0.f ? al1 : 0.2f * al1;
    float al2 = a_s[s2] + adn; al2 = al2 > 0.f ? al2 : 0.2f * al2;
    float al3 = a_s[s3] + adn; al3 = al3 > 0.f ? al3 : 0.2f * al3;
    float w0 = __expf(al0), w1 = __expf(al1);
    float w2 = __expf(al2), w3 = __expf(al3);
    float h0 = b2f(h[s0 * 64 + lane]);
    float h1 = b2f(h[s1 * 64 + lane]);
    float h2 = b2f(h[s2 * 64 + lane]);
    float h3 = b2f(h[s3 * 64 + lane]);
    den += (w0 + w1) + (w2 + w3);
    acc += w0 * h0 + w1 * h1 + w2 * h2 + w3 * h3;
  }
  for (; j < deg; ++j) {
    int s0 = csr_src[start + j];
    float al = a_s[s0] + adn; al = al > 0.f ? al : 0.2f * al;
    float w0 = __expf(al);
    den += w0;
    acc += w0 * b2f(h[s0 * 64 + lane]);
  }
  float v = acc / (den + 1e-16f) + bias[lane];
  v = v > 0.f ? v : expm1f(v);
  xout[n * 64 + lane] = f2b(v);
}

// ---------------- edge MLP (R25: R15 schedule, 320-thread blocks) ----------
// Counted-vmcnt pipeline (schedule unchanged — R13/R14/R16/R18/R19 variants
// all regressed). R25 raises RESIDENT WAVES: at 45 KB LDS the cap is 3
// blocks/CU regardless of block size; 5 waves/block -> 15 waves/CU (+25% vs
// 12). Chunk = 1280 uint4 = 4/thread x 320 (exact). Per-wave in-flight:
// waves 0-3 = 4, wave 4 = 6 (+wsc2). Grid 1875 x 320 = 600000 exact.
__global__ __launch_bounds__(320) void k_edge_mlp(
    const int* __restrict__ eidx, const u16* __restrict__ x2bf,
    const float* __restrict__ eattr, const u16* __restrict__ wm1t,
    const float2* __restrict__ wsc2, const float* __restrict__ w2sum,
    const float* __restrict__ bm2, float* __restrict__ out) {
  __shared__ uint4 Bbuf[2][1408];  // [0..1280): B frags, [1280..1408): wsc2
  int tid = threadIdx.x;
  int lane = tid & 63;
  int wave = tid >> 6;
  int base = blockIdx.x * 320 + wave * 64;
  int m = lane & 15, q = lane >> 4;

  // ---- A fragments (oldest VMEM: gathered edge features) ----
  bf16x8 A[4][4];
#pragma unroll
  for (int s = 0; s < 4; ++s) {
    int row = imin(base + s * 16 + m, KE - 1);
    int es = eidx[row], ed = eidx[KE + row];
    const bf16x8* psrc = (const bf16x8*)(x2bf + es * 64);
    const bf16x8* pdst = (const bf16x8*)(x2bf + ed * 64);
    A[s][0] = psrc[q];
    A[s][1] = psrc[q + 4];
    A[s][2] = pdst[q];
    A[s][3] = pdst[q + 4];
  }
  bf16x8 A5[4];
#pragma unroll
  for (int s = 0; s < 4; ++s) {
    bf16x8 a5 = {0, 0, 0, 0, 0, 0, 0, 0};
    if (q == 0) {
      int row = imin(base + s * 16 + m, KE - 1);
      a5[0] = (__bf16)eattr[row * 2 + 0];
      a5[1] = (__bf16)eattr[row * 2 + 1];
      a5[2] = (__bf16)1.0f;
    }
    A5[s] = a5;
  }

  // ---- stage chunk 0: 4 B-frag loads per thread; wave 4 adds the 2 wsc2 ----
  const uint4* gB = (const uint4*)wm1t;   // chunk ch = uint4 [ch*1280, +1280)
  const uint4* gW = (const uint4*)wsc2;   // chunk ch = uint4 [ch*128, +128)
#pragma unroll
  for (int k = 0; k < 4; ++k)
    gload_lds16(gB + tid + k * 320, &Bbuf[0][tid + k * 320]);
  if (wave == 4) {
    gload_lds16(gW + lane, &Bbuf[0][1280 + lane]);
    gload_lds16(gW + 64 + lane, &Bbuf[0][1280 + 64 + lane]);
  }

  f32x2 osum[4][2];
#pragma unroll
  for (int s = 0; s < 4; ++s) {
    osum[s][0] = (f32x2){0.f, 0.f};
    osum[s][1] = (f32x2){0.f, 0.f};
  }

#pragma unroll 1
  for (int ch = 0; ch < 9; ++ch) {
    int cur = ch & 1, nxt = cur ^ 1;
    // WAR fence: all waves done reading Bbuf[nxt] (chunk ch-1) before restage
    if (ch > 0) __builtin_amdgcn_s_barrier();
    if (ch < 8) {
      const uint4* gs = gB + (ch + 1) * 1280;
#pragma unroll
      for (int k = 0; k < 4; ++k)
        gload_lds16(gs + tid + k * 320, &Bbuf[nxt][tid + k * 320]);
      if (wave == 4) {
        const uint4* ws = gW + (ch + 1) * 128;
        gload_lds16(ws + lane, &Bbuf[nxt][1280 + lane]);
        gload_lds16(ws + 64 + lane, &Bbuf[nxt][1280 + 64 + lane]);
        // wave 4: drain own chunk-ch 6 loads; leave chunk ch+1's 6 in flight
        asm volatile("s_waitcnt vmcnt(6)" ::: "memory");
      } else {
        // waves 0-3: drain own chunk-ch 4 loads; leave chunk ch+1's 4 in flight
        asm volatile("s_waitcnt vmcnt(4)" ::: "memory");
      }
    } else {
      asm volatile("s_waitcnt vmcnt(0)" ::: "memory");
    }
    __builtin_amdgcn_s_barrier();  // all waves' chunk-ch loads landed

    int lim = (ch == 8) ? 1 : 4;
#pragma unroll 1
    for (int li = 0; li < lim; ++li) {
      const bf16x8* lb = (const bf16x8*)(Bbuf[cur] + li * 5 * 64);
      bf16x8 B0 = lb[0 * 64 + lane];
      bf16x8 B1 = lb[1 * 64 + lane];
      bf16x8 B2 = lb[2 * 64 + lane];
      bf16x8 B3 = lb[3 * 64 + lane];
      bf16x8 B4 = lb[4 * 64 + lane];
      float2 w2 = ((const float2*)(Bbuf[cur] + 1280))[li * 64 + lane];
#pragma unroll
      for (int s = 0; s < 4; ++s) {
        f32x4 acc = {0.f, 0.f, 0.f, 0.f};
        acc = __builtin_amdgcn_mfma_f32_16x16x32_bf16(A[s][0], B0, acc, 0, 0, 0);
        acc = __builtin_amdgcn_mfma_f32_16x16x32_bf16(A[s][1], B1, acc, 0, 0, 0);
        acc = __builtin_amdgcn_mfma_f32_16x16x32_bf16(A[s][2], B2, acc, 0, 0, 0);
        acc = __builtin_amdgcn_mfma_f32_16x16x32_bf16(A[s][3], B3, acc, 0, 0, 0);
        acc = __builtin_amdgcn_mfma_f32_16x16x32_bf16(A5[s],   B4, acc, 0, 0, 0);
        f32x2 t0 = {fminf(acc[0], 0.f), fminf(acc[1], 0.f)};
        f32x2 t1 = {fminf(acc[2], 0.f), fminf(acc[3], 0.f)};
        f32x2 e0 = {fexp2(t0.x), fexp2(t0.y)};
        f32x2 e1 = {fexp2(t1.x), fexp2(t1.y)};
        osum[s][0] += e0 * w2.x + t0 * w2.y;
        osum[s][1] += e1 * w2.x + t1 * w2.y;
      }
    }
  }

  const bf16x8* bt = (const bf16x8*)wm1t;
  bf16x8 L0 = bt[(33 * 5 + 0) * 64 + lane];
  bf16x8 L1 = bt[(33 * 5 + 1) * 64 + lane];
  bf16x8 L2 = bt[(33 * 5 + 2) * 64 + lane];
  bf16x8 L3 = bt[(33 * 5 + 3) * 64 + lane];
  bf16x8 L4 = bt[(33 * 5 + 4) * 64 + lane];
  float w2s = w2sum[0];
  float b2v = bm2[0];

#pragma unroll
  for (int s = 0; s < 4; ++s) {
    f32x4 accL = {0.f, 0.f, 0.f, 0.f};
    accL = __builtin_amdgcn_mfma_f32_16x16x32_bf16(A[s][0], L0, accL, 0, 0, 0);
    accL = __builtin_amdgcn_mfma_f32_16x16x32_bf16(A[s][1], L1, accL, 0, 0, 0);
    accL = __builtin_amdgcn_mfma_f32_16x16x32_bf16(A[s][2], L2, accL, 0, 0, 0);
    accL = __builtin_amdgcn_mfma_f32_16x16x32_bf16(A[s][3], L3, accL, 0, 0, 0);
    accL = __builtin_amdgcn_mfma_f32_16x16x32_bf16(A5[s],   L4, accL, 0, 0, 0);
    float ov[4] = {osum[s][0].x, osum[s][0].y, osum[s][1].x, osum[s][1].y};
#pragma unroll
    for (int r = 0; r < 4; ++r) {
      float lin = accL[r] + __shfl_xor(accL[r], 1);
      float v = ov[r];
      v += __shfl_xor(v, 1);
      v += __shfl_xor(v, 2);
      v += __shfl_xor(v, 4);
      v += __shfl_xor(v, 8);
      if (m == 0) {
        int row = base + s * 16 + q * 4 + r;
        if (row < KE) out[row] = v - w2s + lin + b2v;
      }
    }
  }
}

extern "C" void kernel_launch(void* const* d_in, const int* in_sizes, int n_in,
                              void* d_out, int out_size, void* d_ws, size_t ws_size,
                              hipStream_t stream) {
  const float* pos  = (const float*)d_in[0];
  const int* eidx   = (const int*)d_in[1];
  const int* geidx  = (const int*)d_in[2];
  const float* eattr= (const float*)d_in[3];
  const float* W0   = (const float*)d_in[4];
  const float* as0  = (const float*)d_in[5];
  const float* ad0  = (const float*)d_in[6];
  const float* b0   = (const float*)d_in[7];
  const float* W1   = (const float*)d_in[8];
  const float* as1  = (const float*)d_in[9];
  const float* ad1  = (const float*)d_in[10];
  const float* b1   = (const float*)d_in[11];
  const float* Wm1  = (const float*)d_in[12];
  const float* bm1  = (const float*)d_in[13];
  const float* Wm2  = (const float*)d_in[14];
  const float* bm2  = (const float*)d_in[15];
  float* out = (float*)d_out;

  char* ws = (char*)d_ws;
  size_t off = 0;
  auto carve = [&](size_t bytes) {
    char* p = ws + off;
    off = (off + bytes + 255) & ~(size_t)255;
    return p;
  };
  int* counts    = (int*)carve((size_t)KN * 4);    // zeroed by memset below
  int* incl      = (int*)carve((size_t)KN * 4);
  int* row_start = (int*)carve((size_t)KN * 4);
  int* bsum      = (int*)carve(128 * 4);
  int* boff      = (int*)carve(128 * 4);
  int* csr_src   = (int*)carve((size_t)(KEG + 4 * KN) * 4);  // 4-aligned rows pad
  int* tmp_pos   = (int*)carve((size_t)KEG * 4);
  u16* h0        = (u16*)carve((size_t)KN * 64 * 2);
  u16* h1        = (u16*)carve((size_t)KN * 64 * 2);
  u16* x12       = (u16*)carve((size_t)KN * 64 * 2);
  float* a_s0    = (float*)carve((size_t)KN * 4);
  float* a_d0    = (float*)carve((size_t)KN * 4);
  float* a_s1    = (float*)carve((size_t)KN * 4);
  float* a_d1    = (float*)carve((size_t)KN * 4);
  u16* wm1t      = (u16*)carve((size_t)36 * 5 * 512 * 2);  // tiles 34..35 = pad
  u16* w1t       = (u16*)carve((size_t)4 * 2 * 64 * 8 * 2);
  // wsc2: 33*64 float2 live + padding so chunk 8's staged slice (uint4
  // [1024,1152)) stays inside the carve. 36*64*8 = 18432 B = 1152 uint4.
  float2* wsc2   = (float2*)carve((size_t)36 * 64 * 8);
  float* w2sum   = (float*)carve(256);

  const int* gsrc = geidx;
  const int* gdst = geidx + KEG;

  // zero counts (first carve at ws start)
  hipMemsetAsync(d_ws, 0, (size_t)KN * 4, stream);

  // fused front: prep + cvec + hist(+slot capture) + transform0
  k_front<<<FB_PREP + FB_CVEC + FB_HIST + FB_T0, 256, 0, stream>>>(
      pos, W0, as0, ad0, Wm1, bm1, Wm2, W1, gdst,
      wm1t, w1t, wsc2, w2sum, counts, tmp_pos, h0, a_s0, a_d0);

  k_scan_block<<<NB, 1024, 0, stream>>>(counts, incl, bsum);
  k_scan_bsum<<<1, 64, 0, stream>>>(bsum, boff);
  k_scan_final<<<NB, 1024, 0, stream>>>(incl, counts, boff, row_start);
  k_fill<<<(KEG + 255) / 256, 256, 0, stream>>>(gsrc, gdst, row_start, tmp_pos, csr_src);

  // ---- fused GAT layer-0 aggregate + layer-1 transform (16-node blocks) ----
  k_aggt1<<<KN / 16, 256, 0, stream>>>(row_start, counts, csr_src,
                                       a_s0, a_d0, h0, b0,
                                       w1t, as1, ad1, h1, a_s1, a_d1);

  // ---- GAT layer-1 aggregate ----
  k_gat_agg<<<KN / 4, 256, 0, stream>>>(row_start, counts, csr_src, a_s1, a_d1, h1, b1, x12);

  // ---- fused edge MLP (counted-vmcnt pipeline, 320-thread blocks) ----
  k_edge_mlp<<<KE / 320, 320, 0, stream>>>(eidx, x12, eattr, wm1t, wsc2, w2sum, bm2, out);
}

// Round 14
// 350.554 us; speedup vs baseline: 1.3111x; 1.3111x over previous
//
#include <hip/hip_runtime.h>

#define KN 100000
#define KEG 600000
#define KE 600000
#define NB 98  // ceil(KN/1024) scan blocks
#define LOG2E 1.4426950408889634f
#define LN2 0.6931471805599453f

// k_front block ranges
#define FB_PREP 391
#define FB_CVEC 33
#define FB_HIST 2344
#define FB_T0 6250  // 16 nodes/block (4 per wave)

using u16 = unsigned short;
typedef __bf16 bf16x8 __attribute__((ext_vector_type(8)));
typedef float f32x4 __attribute__((ext_vector_type(4)));
typedef float f32x2 __attribute__((ext_vector_type(2)));

__device__ __forceinline__ float b2f(u16 u) { return __uint_as_float(((unsigned)u) << 16); }
__device__ __forceinline__ u16 f2b(float f) {
  unsigned u = __float_as_uint(f);
  u += 0x7FFF + ((u >> 16) & 1);  // round-to-nearest-even
  return (u16)(u >> 16);
}
__device__ __forceinline__ int imin(int a, int b) { return a < b ? a : b; }
__device__ __forceinline__ float fexp2(float x) {
#if __has_builtin(__builtin_amdgcn_exp2f)
  return __builtin_amdgcn_exp2f(x);
#else
  return __expf(x * LN2);
#endif
}

// async global->LDS 16B copy (no VGPR round-trip). LDS dest is wave-uniform
// base + lane*16; callers pass per-lane pointers laid out exactly that way.
__device__ __forceinline__ void gload_lds16(const void* g, void* l) {
  __builtin_amdgcn_global_load_lds(
      (const __attribute__((address_space(1))) unsigned int*)g,
      (__attribute__((address_space(3))) unsigned int*)l,
      16, 0, 0);
}

// ---------------- fused front: prep + cvec + hist + transform0 ----------------
// wm1t: 36 tiles x 5 frags x 512 (tiles 34..35 = staging pad, never computed).
// Tiles 0..32: Wm1 rows 0..127 (frags 0..3) and K-ext rows [w128,w129,bm1]
// (frag 4), ALL x LOG2E. Tile 33 (owned by cvec range): linear composite
// c=B160@wm2 natural units, c_hi col0 / c_lo col1.
// R21: hist captures the atomicAdd return (slot within dst row) -> tmp_pos[e],
// making k_fill atomic-free. R24: transform0 = 6250 blocks x 16 nodes.
__global__ __launch_bounds__(256) void k_front(
    const float* __restrict__ pos, const float* __restrict__ W0,
    const float* __restrict__ att_s, const float* __restrict__ att_d,
    const float* __restrict__ wm1, const float* __restrict__ bm1,
    const float* __restrict__ wm2, const float* __restrict__ w1,
    const int* __restrict__ gdst,
    u16* __restrict__ wm1t, u16* __restrict__ w1t, float2* __restrict__ wsc2,
    float* __restrict__ w2sum, int* __restrict__ counts, int* __restrict__ tmp_pos,
    u16* __restrict__ h, float* __restrict__ a_s, float* __restrict__ a_d) {
  int bid = blockIdx.x;
  if (bid < FB_PREP) {
    int idx = bid * 256 + threadIdx.x;
    if (idx < 33 * 5 * 512) {  // tiles 0..32 only
      int j = idx & 7;
      int lane = (idx >> 3) & 63;
      int f = (idx >> 9) % 5;
      int nt = idx / (512 * 5);
      int n = nt * 16 + (lane & 15);
      float v = 0.f;
      if (n < 520) {
        if (f < 4) {
          int k = f * 32 + (lane >> 4) * 8 + j;
          v = wm1[k * 520 + n] * LOG2E;
        } else {
          int kk = (lane >> 4) * 8 + j;
          if (kk == 0) v = wm1[128 * 520 + n] * LOG2E;
          else if (kk == 1) v = wm1[129 * 520 + n] * LOG2E;
          else if (kk == 2) v = bm1[n] * LOG2E;
        }
      }
      wm1t[idx] = f2b(v);
    }
    if (idx < 33 * 64) {
      int lane = idx & 63, nt = idx >> 6;
      int col = nt * 16 + (lane & 15);
      float w2 = (col < 520) ? wm2[col] : 0.f;
      float2 p; p.x = w2; p.y = -LN2 * w2;
      wsc2[idx] = p;
    }
    if (idx < 4 * 2 * 64 * 8) {  // W1 -> MFMA B frags
      int j = idx & 7;
      int lane = (idx >> 3) & 63;
      int kt = (idx >> 9) & 1;
      int nt = idx >> 10;
      int n = nt * 16 + (lane & 15);
      int k = kt * 32 + (lane >> 4) * 8 + j;
      w1t[idx] = f2b(w1[k * 64 + n]);
    }
  } else if (bid < FB_PREP + FB_CVEC) {
    // cvec: c_k = sum_h B160[k][h]*wm2[h]; w = row index 0..130; w==131 -> w2sum
    int lane = threadIdx.x & 63;
    int w = (bid - FB_PREP) * 4 + (threadIdx.x >> 6);
    float x = 0.f;
    if (w <= 129) {
      const float* row = wm1 + (size_t)w * 520;
#pragma unroll
      for (int j = 0; j < 8; ++j) x += row[j * 64 + lane] * wm2[j * 64 + lane];
      if (lane < 8) x += row[512 + lane] * wm2[512 + lane];
    } else if (w == 130) {
#pragma unroll
      for (int j = 0; j < 8; ++j) x += bm1[j * 64 + lane] * wm2[j * 64 + lane];
      if (lane < 8) x += bm1[512 + lane] * wm2[512 + lane];
    } else if (w == 131) {
#pragma unroll
      for (int j = 0; j < 8; ++j) x += wm2[j * 64 + lane];
      if (lane < 8) x += wm2[512 + lane];
    }
    for (int off = 1; off < 64; off <<= 1) x += __shfl_xor(x, off);
    if (w <= 130 && lane < 16) {
      int f = w >> 5, kk = w & 31;
      int qq = kk >> 3, jj = kk & 7;
      u16 chi = f2b(x);
      float v = (lane == 0) ? x : (lane == 1 ? (x - b2f(chi)) : 0.f);
      wm1t[(33 * 5 + f) * 512 + (qq * 16 + lane) * 8 + jj] = f2b(v);
    } else if (w == 131 && lane == 0) {
      w2sum[0] = x;
    }
  } else if (bid < FB_PREP + FB_CVEC + FB_HIST) {
    int e = (bid - (FB_PREP + FB_CVEC)) * 256 + threadIdx.x;
    if (e < KEG) tmp_pos[e] = atomicAdd(counts + gdst[e], 1);
  } else {
    // transform0: h = pos @ W0, a_s/a_d reductions. 6250 blocks x 16 nodes
    // (4 per wave, per-node math identical to the 1-node/wave version).
    int lane = threadIdx.x & 63;
    int wave = threadIdx.x >> 6;
    int nb = (bid - (FB_PREP + FB_CVEC + FB_HIST)) * 16 + wave * 4;
#pragma unroll
    for (int i = 0; i < 4; ++i) {
      int n = nb + i;
      float p0 = pos[n * 3 + 0], p1 = pos[n * 3 + 1], p2 = pos[n * 3 + 2];
      float hv = p0 * W0[lane] + p1 * W0[64 + lane] + p2 * W0[128 + lane];
      h[n * 64 + lane] = f2b(hv);
      float s = hv * att_s[lane];
      float d = hv * att_d[lane];
      for (int off = 1; off < 64; off <<= 1) { s += __shfl_xor(s, off); d += __shfl_xor(d, off); }
      if (lane == 0) { a_s[n] = s; a_d[n] = d; }
    }
  }
}

// ---------------- CSR build (R24: rows padded to 4 -> int4 group loads) ----
// Scan runs over cp = (count+3)&~3 so every row_start is 4-aligned; deg stays
// exact (counts); pad slots are never read (walks bounded by deg).

__global__ __launch_bounds__(1024) void k_scan_block(
    const int* __restrict__ counts, int* __restrict__ incl, int* __restrict__ bsum) {
  int gid = blockIdx.x * 1024 + threadIdx.x;
  int lane = threadIdx.x & 63, w = threadIdx.x >> 6;
  int x = (gid < KN) ? ((counts[gid] + 3) & ~3) : 0;
  for (int off = 1; off < 64; off <<= 1) {
    int y = __shfl_up(x, off);
    if (lane >= off) x += y;
  }
  __shared__ int wtot[16];
  if (lane == 63) wtot[w] = x;
  __syncthreads();
  if (w == 0 && lane < 16) {
    int t = wtot[lane];
    for (int off = 1; off < 16; off <<= 1) {
      int y = __shfl_up(t, off);
      if (lane >= off) t += y;
    }
    wtot[lane] = t;
  }
  __syncthreads();
  if (w > 0) x += wtot[w - 1];
  if (gid < KN) incl[gid] = x;
  if (threadIdx.x == 1023) bsum[blockIdx.x] = x;
}

__global__ __launch_bounds__(64) void k_scan_bsum(const int* __restrict__ bsum, int* __restrict__ boff) {
  int lane = threadIdx.x;
  int x0 = (lane < NB) ? bsum[lane] : 0;
  int x1 = (64 + lane < NB) ? bsum[64 + lane] : 0;
  int i0 = x0, i1 = x1;
  for (int off = 1; off < 64; off <<= 1) {
    int y0 = __shfl_up(i0, off), y1 = __shfl_up(i1, off);
    if (lane >= off) { i0 += y0; i1 += y1; }
  }
  int tot0 = __shfl(i0, 63);
  if (lane < NB) boff[lane] = i0 - x0;
  if (64 + lane < NB) boff[64 + lane] = i1 - x1 + tot0;
}

__global__ __launch_bounds__(1024) void k_scan_final(
    const int* __restrict__ incl, const int* __restrict__ counts,
    const int* __restrict__ boff, int* __restrict__ row_start) {
  int gid = blockIdx.x * 1024 + threadIdx.x;
  if (gid < KN) {
    int cp = (counts[gid] + 3) & ~3;
    row_start[gid] = incl[gid] - cp + boff[blockIdx.x];
  }
}

// fill CSR (R21): ATOMIC-FREE — slot was captured during the hist pass.
__global__ __launch_bounds__(256) void k_fill(
    const int* __restrict__ gsrc, const int* __restrict__ gdst,
    const int* __restrict__ row_start, const int* __restrict__ tmp_pos,
    int* __restrict__ csr_src) {
  int e = blockIdx.x * 256 + threadIdx.x;
  if (e >= KEG) return;
  int d = gdst[e];
  csr_src[row_start[d] + tmp_pos[e]] = gsrc[e];
}

// ---------------- GAT layers ----------------

// FUSED agg(L0) + transform1. Block = 16 nodes, grid 6250; each wave
// aggregates 4 nodes (phase A), then computes one column tile (phase B).
// 4-aligned rows -> int4 group index loads.
__global__ __launch_bounds__(256) void k_aggt1(
    const int* __restrict__ row_start, const int* __restrict__ counts,
    const int* __restrict__ csr_src, const float* __restrict__ a_s0,
    const float* __restrict__ a_d0, const u16* __restrict__ h0,
    const float* __restrict__ b0, const u16* __restrict__ w1t,
    const float* __restrict__ as1, const float* __restrict__ ad1,
    u16* __restrict__ h1, float* __restrict__ a_s1, float* __restrict__ a_d1) {
  __shared__ u16 xb[16][72];        // 16 rows x (64 + 8 pad) bf16 = 2304 B
  __shared__ float psum[2][4][16];  // [s/d][wave][node] partials, 512 B
  int lane = threadIdx.x & 63;
  int wave = threadIdx.x >> 6;
  int nodebase = blockIdx.x * 16;   // grid 6250 -> 16*6250 = 100000 exactly

  // ---- phase A: each wave aggregates 4 nodes (lane = channel) ----
  int st0 = row_start[nodebase + wave * 4 + 0];
  int st1 = row_start[nodebase + wave * 4 + 1];
  int st2 = row_start[nodebase + wave * 4 + 2];
  int st3 = row_start[nodebase + wave * 4 + 3];
  int dg0 = counts[nodebase + wave * 4 + 0];
  int dg1 = counts[nodebase + wave * 4 + 1];
  int dg2 = counts[nodebase + wave * 4 + 2];
  int dg3 = counts[nodebase + wave * 4 + 3];
  float adn0 = a_d0[nodebase + wave * 4 + 0];
  float adn1 = a_d0[nodebase + wave * 4 + 1];
  float adn2 = a_d0[nodebase + wave * 4 + 2];
  float adn3 = a_d0[nodebase + wave * 4 + 3];
#pragma unroll
  for (int i = 0; i < 4; ++i) {
    int start = i == 0 ? st0 : (i == 1 ? st1 : (i == 2 ? st2 : st3));
    int deg   = i == 0 ? dg0 : (i == 1 ? dg1 : (i == 2 ? dg2 : dg3));
    float adn = i == 0 ? adn0 : (i == 1 ? adn1 : (i == 2 ? adn2 : adn3));
    float acc = 0.f, den = 0.f;
    int j = 0;
    for (; j + 4 <= deg; j += 4) {
      int4 sv = *(const int4*)(csr_src + start + j);  // 4-aligned row
      int s0 = sv.x, s1 = sv.y, s2 = sv.z, s3 = sv.w;
      float al0 = a_s0[s0] + adn; al0 = al0 > 0.f ? al0 : 0.2f * al0;
      float al1 = a_s0[s1] + adn; al1 = al1 > 0.f ? al1 : 0.2f * al1;
      float al2 = a_s0[s2] + adn; al2 = al2 > 0.f ? al2 : 0.2f * al2;
      float al3 = a_s0[s3] + adn; al3 = al3 > 0.f ? al3 : 0.2f * al3;
      float w0 = __expf(al0), w1 = __expf(al1);
      float w2 = __expf(al2), w3 = __expf(al3);
      float h0v = b2f(h0[s0 * 64 + lane]);
      float h1v = b2f(h0[s1 * 64 + lane]);
      float h2v = b2f(h0[s2 * 64 + lane]);
      float h3v = b2f(h0[s3 * 64 + lane]);
      den += (w0 + w1) + (w2 + w3);
      acc += w0 * h0v + w1 * h1v + w2 * h2v + w3 * h3v;
    }
    for (; j < deg; ++j) {
      int s0 = csr_src[start + j];
      float al = a_s0[s0] + adn; al = al > 0.f ? al : 0.2f * al;
      float w0 = __expf(al);
      den += w0;
      acc += w0 * b2f(h0[s0 * 64 + lane]);
    }
    float v = acc / (den + 1e-16f) + b0[lane];
    v = v > 0.f ? v : expm1f(v);
    xb[wave * 4 + i][lane] = f2b(v);
  }
  __syncthreads();  // all 16 rows visible to all waves

  // ---- phase B: wave w computes column tile nt=w for all 16 nodes ----
  int m = lane & 15, q = lane >> 4;
  const u16* row = xb[m];
  bf16x8 A0 = *(const bf16x8*)(row + q * 8);       // k 0..31
  bf16x8 A1 = *(const bf16x8*)(row + 32 + q * 8);  // k 32..63

  const bf16x8* bt = (const bf16x8*)w1t;
  int nt = wave;
  int col = nt * 16 + m;
  float asv = as1[col], adv = ad1[col];
  f32x4 acc = {0.f, 0.f, 0.f, 0.f};
  acc = __builtin_amdgcn_mfma_f32_16x16x32_bf16(A0, bt[(nt * 2 + 0) * 64 + lane], acc, 0, 0, 0);
  acc = __builtin_amdgcn_mfma_f32_16x16x32_bf16(A1, bt[(nt * 2 + 1) * 64 + lane], acc, 0, 0, 0);
#pragma unroll
  for (int r = 0; r < 4; ++r) {  // C/D: col=lane&15, row(node)=q*4+r
    int rown = nodebase + q * 4 + r;
    h1[rown * 64 + col] = f2b(acc[r]);
    float s = acc[r] * asv, d = acc[r] * adv;
    s += __shfl_xor(s, 1); d += __shfl_xor(d, 1);
    s += __shfl_xor(s, 2); d += __shfl_xor(d, 2);
    s += __shfl_xor(s, 4); d += __shfl_xor(d, 4);
    s += __shfl_xor(s, 8); d += __shfl_xor(d, 8);
    if (m == 0) { psum[0][wave][q * 4 + r] = s; psum[1][wave][q * 4 + r] = d; }
  }
  __syncthreads();

  // ---- cross-wave reduction of a_s1/a_d1 partials ----
  if (threadIdx.x < 16) {
    int i = threadIdx.x;
    a_s1[nodebase + i] = psum[0][0][i] + psum[0][1][i] + psum[0][2][i] + psum[0][3][i];
    a_d1[nodebase + i] = psum[1][0][i] + psum[1][1][i] + psum[1][2][i] + psum[1][3][i];
  }
}

// aggregate layer 1 (weights inline, 4-way ILP, int4 idx loads) -> x12 bf16.
__global__ __launch_bounds__(256) void k_gat_agg(
    const int* __restrict__ row_start, const int* __restrict__ counts,
    const int* __restrict__ csr_src, const float* __restrict__ a_s,
    const float* __restrict__ a_d, const u16* __restrict__ h,
    const float* __restrict__ bias, u16* __restrict__ xout) {
  int lane = threadIdx.x & 63;
  int n = blockIdx.x * 4 + (threadIdx.x >> 6);  // grid covers KN exactly
  int start = row_start[n], deg = counts[n];
  float adn = a_d[n];
  float acc = 0.f, den = 0.f;
  int j = 0;
  for (; j + 4 <= deg; j += 4) {
    int4 sv = *(const int4*)(csr_src + start + j);  // 4-aligned row
    int s0 = sv.x, s1 = sv.y, s2 = sv.z, s3 = sv.w;
    float al0 = a_s[s0] + adn; al0 = al0 > 0.f ? al0 : 0.2f * al0;
    float al1 = a_s[s1] + adn; al1 = al1 > 0.f ? al1 : 0.2f * al1;
    float al2 = a_s[s2] + adn; al2 = al2 > 0.f ? al2 : 0.2f * al2;
    float al3 = a_s[s3] + adn; al3 = al3 > 0.f ? al3 : 0.2f * al3;
    float w0 = __expf(al0), w1 = __expf(al1);
    float w2 = __expf(al2), w3 = __expf(al3);
    float h0 = b2f(h[s0 * 64 + lane]);
    float h1 = b2f(h[s1 * 64 + lane]);
    float h2 = b2f(h[s2 * 64 + lane]);
    float h3 = b2f(h[s3 * 64 + lane]);
    den += (w0 + w1) + (w2 + w3);
    acc += w0 * h0 + w1 * h1 + w2 * h2 + w3 * h3;
  }
  for (; j < deg; ++j) {
    int s0 = csr_src[start + j];
    float al = a_s[s0] + adn; al = al > 0.f ? al : 0.2f * al;
    float w0 = __expf(al);
    den += w0;
    acc += w0 * b2f(h[s0 * 64 + lane]);
  }
  float v = acc / (den + 1e-16f) + bias[lane];
  v = v > 0.f ? v : expm1f(v);
  xout[n * 64 + lane] = f2b(v);
}

// ---------------- edge MLP (R15 structure + R22 wsc2-dedup; measured best) --
// Counted-vmcnt pipeline. __syncthreads() forces vmcnt(0), draining the chunk
// ch+1 prefetch; replaced with raw s_barrier + counted s_waitcnt so prefetch
// stays in flight across both barriers and the whole compute of chunk ch.
// wsc2 slice staged by wave 3 only; per-wave in-flight counts 5/5/5/7.
// R13/R14/R16/R18/R19/R25 structural variants ALL regressed; do not touch.
__global__ __launch_bounds__(256) void k_edge_mlp(
    const int* __restrict__ eidx, const u16* __restrict__ x2bf,
    const float* __restrict__ eattr, const u16* __restrict__ wm1t,
    const float2* __restrict__ wsc2, const float* __restrict__ w2sum,
    const float* __restrict__ bm2, float* __restrict__ out) {
  __shared__ uint4 Bbuf[2][1408];  // [0..1280): B frags, [1280..1408): wsc2
  int tid = threadIdx.x;
  int lane = tid & 63;
  int wave = tid >> 6;
  int base = blockIdx.x * 256 + wave * 64;
  int m = lane & 15, q = lane >> 4;

  // ---- A fragments (oldest VMEM: gathered edge features) ----
  bf16x8 A[4][4];
#pragma unroll
  for (int s = 0; s < 4; ++s) {
    int row = imin(base + s * 16 + m, KE - 1);
    int es = eidx[row], ed = eidx[KE + row];
    const bf16x8* psrc = (const bf16x8*)(x2bf + es * 64);
    const bf16x8* pdst = (const bf16x8*)(x2bf + ed * 64);
    A[s][0] = psrc[q];
    A[s][1] = psrc[q + 4];
    A[s][2] = pdst[q];
    A[s][3] = pdst[q + 4];
  }
  bf16x8 A5[4];
#pragma unroll
  for (int s = 0; s < 4; ++s) {
    bf16x8 a5 = {0, 0, 0, 0, 0, 0, 0, 0};
    if (q == 0) {
      int row = imin(base + s * 16 + m, KE - 1);
      a5[0] = (__bf16)eattr[row * 2 + 0];
      a5[1] = (__bf16)eattr[row * 2 + 1];
      a5[2] = (__bf16)1.0f;
    }
    A5[s] = a5;
  }

  // ---- stage chunk 0: 5 B-frag loads per wave; wave 3 adds the 2 wsc2 ----
  const uint4* gB = (const uint4*)wm1t;   // chunk ch = uint4 [ch*1280, +1280)
  const uint4* gW = (const uint4*)wsc2;   // chunk ch = uint4 [ch*128, +128)
#pragma unroll
  for (int k = 0; k < 5; ++k)
    gload_lds16(gB + tid + k * 256, &Bbuf[0][tid + k * 256]);
  if (wave == 3) {
    gload_lds16(gW + lane, &Bbuf[0][1280 + lane]);
    gload_lds16(gW + 64 + lane, &Bbuf[0][1280 + 64 + lane]);
  }

  f32x2 osum[4][2];
#pragma unroll
  for (int s = 0; s < 4; ++s) {
    osum[s][0] = (f32x2){0.f, 0.f};
    osum[s][1] = (f32x2){0.f, 0.f};
  }

#pragma unroll 1
  for (int ch = 0; ch < 9; ++ch) {
    int cur = ch & 1, nxt = cur ^ 1;
    // WAR fence: all waves done reading Bbuf[nxt] (chunk ch-1) before restage
    if (ch > 0) __builtin_amdgcn_s_barrier();
    if (ch < 8) {
      const uint4* gs = gB + (ch + 1) * 1280;
#pragma unroll
      for (int k = 0; k < 5; ++k)
        gload_lds16(gs + tid + k * 256, &Bbuf[nxt][tid + k * 256]);
      if (wave == 3) {
        const uint4* ws = gW + (ch + 1) * 128;
        gload_lds16(ws + lane, &Bbuf[nxt][1280 + lane]);
        gload_lds16(ws + 64 + lane, &Bbuf[nxt][1280 + 64 + lane]);
        // wave 3: drain own chunk-ch 7 loads; leave chunk ch+1's 7 in flight
        asm volatile("s_waitcnt vmcnt(7)" ::: "memory");
      } else {
        // waves 0-2: drain own chunk-ch 5 loads; leave chunk ch+1's 5 in flight
        asm volatile("s_waitcnt vmcnt(5)" ::: "memory");
      }
    } else {
      asm volatile("s_waitcnt vmcnt(0)" ::: "memory");
    }
    __builtin_amdgcn_s_barrier();  // all waves' chunk-ch loads landed

    int lim = (ch == 8) ? 1 : 4;
#pragma unroll 1
    for (int li = 0; li < lim; ++li) {
      const bf16x8* lb = (const bf16x8*)(Bbuf[cur] + li * 5 * 64);
      bf16x8 B0 = lb[0 * 64 + lane];
      bf16x8 B1 = lb[1 * 64 + lane];
      bf16x8 B2 = lb[2 * 64 + lane];
      bf16x8 B3 = lb[3 * 64 + lane];
      bf16x8 B4 = lb[4 * 64 + lane];
      float2 w2 = ((const float2*)(Bbuf[cur] + 1280))[li * 64 + lane];
#pragma unroll
      for (int s = 0; s < 4; ++s) {
        f32x4 acc = {0.f, 0.f, 0.f, 0.f};
        acc = __builtin_amdgcn_mfma_f32_16x16x32_bf16(A[s][0], B0, acc, 0, 0, 0);
        acc = __builtin_amdgcn_mfma_f32_16x16x32_bf16(A[s][1], B1, acc, 0, 0, 0);
        acc = __builtin_amdgcn_mfma_f32_16x16x32_bf16(A[s][2], B2, acc, 0, 0, 0);
        acc = __builtin_amdgcn_mfma_f32_16x16x32_bf16(A[s][3], B3, acc, 0, 0, 0);
        acc = __builtin_amdgcn_mfma_f32_16x16x32_bf16(A5[s],   B4, acc, 0, 0, 0);
        f32x2 t0 = {fminf(acc[0], 0.f), fminf(acc[1], 0.f)};
        f32x2 t1 = {fminf(acc[2], 0.f), fminf(acc[3], 0.f)};
        f32x2 e0 = {fexp2(t0.x), fexp2(t0.y)};
        f32x2 e1 = {fexp2(t1.x), fexp2(t1.y)};
        osum[s][0] += e0 * w2.x + t0 * w2.y;
        osum[s][1] += e1 * w2.x + t1 * w2.y;
      }
    }
  }

  const bf16x8* bt = (const bf16x8*)wm1t;
  bf16x8 L0 = bt[(33 * 5 + 0) * 64 + lane];
  bf16x8 L1 = bt[(33 * 5 + 1) * 64 + lane];
  bf16x8 L2 = bt[(33 * 5 + 2) * 64 + lane];
  bf16x8 L3 = bt[(33 * 5 + 3) * 64 + lane];
  bf16x8 L4 = bt[(33 * 5 + 4) * 64 + lane];
  float w2s = w2sum[0];
  float b2v = bm2[0];

#pragma unroll
  for (int s = 0; s < 4; ++s) {
    f32x4 accL = {0.f, 0.f, 0.f, 0.f};
    accL = __builtin_amdgcn_mfma_f32_16x16x32_bf16(A[s][0], L0, accL, 0, 0, 0);
    accL = __builtin_amdgcn_mfma_f32_16x16x32_bf16(A[s][1], L1, accL, 0, 0, 0);
    accL = __builtin_amdgcn_mfma_f32_16x16x32_bf16(A[s][2], L2, accL, 0, 0, 0);
    accL = __builtin_amdgcn_mfma_f32_16x16x32_bf16(A[s][3], L3, accL, 0, 0, 0);
    accL = __builtin_amdgcn_mfma_f32_16x16x32_bf16(A5[s],   L4, accL, 0, 0, 0);
    float ov[4] = {osum[s][0].x, osum[s][0].y, osum[s][1].x, osum[s][1].y};
#pragma unroll
    for (int r = 0; r < 4; ++r) {
      float lin = accL[r] + __shfl_xor(accL[r], 1);
      float v = ov[r];
      v += __shfl_xor(v, 1);
      v += __shfl_xor(v, 2);
      v += __shfl_xor(v, 4);
      v += __shfl_xor(v, 8);
      if (m == 0) {
        int row = base + s * 16 + q * 4 + r;
        if (row < KE) out[row] = v - w2s + lin + b2v;
      }
    }
  }
}

extern "C" void kernel_launch(void* const* d_in, const int* in_sizes, int n_in,
                              void* d_out, int out_size, void* d_ws, size_t ws_size,
                              hipStream_t stream) {
  const float* pos  = (const float*)d_in[0];
  const int* eidx   = (const int*)d_in[1];
  const int* geidx  = (const int*)d_in[2];
  const float* eattr= (const float*)d_in[3];
  const float* W0   = (const float*)d_in[4];
  const float* as0  = (const float*)d_in[5];
  const float* ad0  = (const float*)d_in[6];
  const float* b0   = (const float*)d_in[7];
  const float* W1   = (const float*)d_in[8];
  const float* as1  = (const float*)d_in[9];
  const float* ad1  = (const float*)d_in[10];
  const float* b1   = (const float*)d_in[11];
  const float* Wm1  = (const float*)d_in[12];
  const float* bm1  = (const float*)d_in[13];
  const float* Wm2  = (const float*)d_in[14];
  const float* bm2  = (const float*)d_in[15];
  float* out = (float*)d_out;

  char* ws = (char*)d_ws;
  size_t off = 0;
  auto carve = [&](size_t bytes) {
    char* p = ws + off;
    off = (off + bytes + 255) & ~(size_t)255;
    return p;
  };
  int* counts    = (int*)carve((size_t)KN * 4);    // zeroed by memset below
  int* incl      = (int*)carve((size_t)KN * 4);
  int* row_start = (int*)carve((size_t)KN * 4);
  int* bsum      = (int*)carve(128 * 4);
  int* boff      = (int*)carve(128 * 4);
  int* csr_src   = (int*)carve((size_t)(KEG + 4 * KN) * 4);  // 4-aligned rows pad
  int* tmp_pos   = (int*)carve((size_t)KEG * 4);
  u16* h0        = (u16*)carve((size_t)KN * 64 * 2);
  u16* h1        = (u16*)carve((size_t)KN * 64 * 2);
  u16* x12       = (u16*)carve((size_t)KN * 64 * 2);
  float* a_s0    = (float*)carve((size_t)KN * 4);
  float* a_d0    = (float*)carve((size_t)KN * 4);
  float* a_s1    = (float*)carve((size_t)KN * 4);
  float* a_d1    = (float*)carve((size_t)KN * 4);
  u16* wm1t      = (u16*)carve((size_t)36 * 5 * 512 * 2);  // tiles 34..35 = pad
  u16* w1t       = (u16*)carve((size_t)4 * 2 * 64 * 8 * 2);
  // wsc2: 33*64 float2 live + padding so chunk 8's staged slice (uint4
  // [1024,1152)) stays inside the carve. 36*64*8 = 18432 B = 1152 uint4.
  float2* wsc2   = (float2*)carve((size_t)36 * 64 * 8);
  float* w2sum   = (float*)carve(256);

  const int* gsrc = geidx;
  const int* gdst = geidx + KEG;

  // zero counts (first carve at ws start)
  hipMemsetAsync(d_ws, 0, (size_t)KN * 4, stream);

  // fused front: prep + cvec + hist(+slot capture) + transform0
  k_front<<<FB_PREP + FB_CVEC + FB_HIST + FB_T0, 256, 0, stream>>>(
      pos, W0, as0, ad0, Wm1, bm1, Wm2, W1, gdst,
      wm1t, w1t, wsc2, w2sum, counts, tmp_pos, h0, a_s0, a_d0);

  k_scan_block<<<NB, 1024, 0, stream>>>(counts, incl, bsum);
  k_scan_bsum<<<1, 64, 0, stream>>>(bsum, boff);
  k_scan_final<<<NB, 1024, 0, stream>>>(incl, counts, boff, row_start);
  k_fill<<<(KEG + 255) / 256, 256, 0, stream>>>(gsrc, gdst, row_start, tmp_pos, csr_src);

  // ---- fused GAT layer-0 aggregate + layer-1 transform (16-node blocks) ----
  k_aggt1<<<KN / 16, 256, 0, stream>>>(row_start, counts, csr_src,
                                       a_s0, a_d0, h0, b0,
                                       w1t, as1, ad1, h1, a_s1, a_d1);

  // ---- GAT layer-1 aggregate ----
  k_gat_agg<<<KN / 4, 256, 0, stream>>>(row_start, counts, csr_src, a_s1, a_d1, h1, b1, x12);

  // ---- fused edge MLP (counted-vmcnt pipeline + wsc2-dedup, f32 out) ----
  k_edge_mlp<<<(KE + 255) / 256, 256, 0, stream>>>(eidx, x12, eattr, wm1t, wsc2, w2sum, bm2, out);
}